// Round 8
// baseline (431.425 us; speedup 1.0000x reference)
//
#include <hip/hip_runtime.h>
#include <math.h>

#define NB      512
#define NELEC   30
#define NATOMS  10
#define NNEN    40      // en graph nodes: 30 electrons + 10 atoms
#define FEAT    64
#define KRBF    64
#define BLOCK   1024
#define NWAVES  (BLOCK/64)
#define NPEE    435     // unique elec-elec pairs
#define NPEN    300     // unique elec-nuc pairs
#define TILE    32      // feature tile resident in fT
#define FPAD    33      // fT row stride (+1): banks (p+ff)%32 -> 2-way = free

// ---------------- LDS layout (floats) ----------------
// kee(double)@0 | h[40][64] | agg[40][64] | fT[435][33]
// 19479 floats = 77916 B  ->  2 blocks/CU (155832 <= 163840), 32 waves/CU.
// Grid = 512 = 256 CUs x 2 -> ALL blocks co-resident, single round, no tail.
#define OFF_KEE  0
#define H_OFF    4
#define AGG_OFF  (H_OFF + NNEN*FEAT)       // 2564
#define FT_OFF   (AGG_OFF + NNEN*FEAT)     // 5124
#define SM_TOTAL (FT_OFF + NPEE*FPAD)      // 19479

// triangular pair index base for row i (i<j pairs of 30 electrons)
__device__ __forceinline__ int ee_base(int i) { return 29*i - ((i*(i-1))>>1); }

// ==========================================================================
// RBF filter for one pair, one 32-feature tile (uoff = 0 or 32, literal at
// every call site -> wf/bf rows are compile-time-uniform s_loads).
// facc[32] is born and dies INSIDE one barrier segment (R5 lesson: no
// register state may cross __syncthreads with this allocator).
// FP value sequence identical to all passing rounds.
// ==========================================================================
__device__ __forceinline__ void rbf_filter(float dd, const float* __restrict__ wf,
                                           const float* __restrict__ bf,
                                           int uoff, float* __restrict__ dstrow)
{
    float facc[TILE];
    const float* bfH = bf + uoff;                    // uniform -> s_load
    #pragma unroll
    for (int f = 0; f < TILE; ++f) facc[f] = bfH[f];
    #pragma unroll 4
    for (int k = 0; k < KRBF; ++k) {
        const float ck = (float)((double)k * (8.0/63.0));
        const float t  = dd - ck;
        const float rk = expf(-t*t);
        const float* wrow = wf + k*FEAT + uoff;      // uniform row -> s_load
        #pragma unroll
        for (int f = 0; f < TILE; ++f) facc[f] = fmaf(rk, wrow[f], facc[f]);
    }
    #pragma unroll
    for (int ff = 0; ff < TILE; ++ff) dstrow[ff] = tanhf(facc[ff]);
}

// filter one tile of the ee pair set: threads 0..434, tile uoff
__device__ __forceinline__ void ee_filter_tile(const float* __restrict__ posB,
                                               const float* __restrict__ wf,
                                               const float* __restrict__ bf,
                                               int uoff, float* __restrict__ fT,
                                               int tid)
{
    if (tid < NPEE) {
        int i = 0, rem = tid;
        while (rem >= NELEC - 1 - i) { rem -= NELEC - 1 - i; ++i; }
        const int j = i + 1 + rem;
        const float dx = posB[3*i+0] - posB[3*j+0];
        const float dy = posB[3*i+1] - posB[3*j+1];
        const float dz = posB[3*i+2] - posB[3*j+2];
        const float dd = sqrtf(dx*dx + dy*dy + dz*dz);
        rbf_filter(dd, wf, bf, uoff, fT + tid*FPAD);
    }
}

// filter one tile of the en pair set: threads 0..299 (pair = a*30+e)
__device__ __forceinline__ void en_filter_tile(const float* __restrict__ posB,
                                               const float* __restrict__ atoms,
                                               const float* __restrict__ wf,
                                               const float* __restrict__ bf,
                                               int uoff, float* __restrict__ fT,
                                               int tid)
{
    if (tid < NPEN) {
        const int a = tid / NELEC;
        const int e = tid - a*NELEC;
        const float dx = posB[3*e+0] - atoms[3*a+0];
        const float dy = posB[3*e+1] - atoms[3*a+1];
        const float dz = posB[3*e+2] - atoms[3*a+2];
        const float dd = sqrtf(dx*dx + dy*dy + dz*dz);
        rbf_filter(dd, wf, bf, uoff, fT + tid*FPAD);
    }
}

// ee messages, one feature tile: thread (i, ff), f = t*32+ff; j ascending
__device__ __forceinline__ void ee_msg_tile(const float* __restrict__ h,
                                            float* __restrict__ agg,
                                            const float* __restrict__ fT,
                                            int t, int tid)
{
    if (tid < NELEC*TILE) {
        const int i  = tid >> 5;
        const int ff = tid & 31;
        const int f  = t*TILE + ff;
        float a = 0.f;
        #pragma unroll
        for (int j = 0; j < NELEC; ++j) {
            if (j != i) {
                int pp = (j < i) ? (ee_base(j) + (i - j - 1))
                                 : (ee_base(i) + (j - i - 1));
                a = fmaf(h[j*FEAT + f], fT[pp*FPAD + ff], a);
            }
        }
        agg[i*FEAT + f] = a;
    }
}

// en messages, one feature tile: 40 nodes x 32 ff = 1280 items, 2 passes
__device__ __forceinline__ void en_msg_tile(const float* __restrict__ h,
                                            float* __restrict__ agg,
                                            const float* __restrict__ fT,
                                            int t, int tid)
{
    #pragma unroll
    for (int pass = 0; pass < 2; ++pass) {
        const int idx = tid + pass*BLOCK;
        if (idx < NNEN*TILE) {
            const int n  = idx >> 5;
            const int ff = idx & 31;
            const int f  = t*TILE + ff;
            float a = 0.f;
            if (n < NELEC) {            // electron node: atoms ascending
                #pragma unroll
                for (int at = 0; at < NATOMS; ++at)
                    a = fmaf(h[(NELEC+at)*FEAT + f],
                             fT[(at*NELEC + n)*FPAD + ff], a);
            } else {                    // atom node: electrons ascending
                const int at = n - NELEC;
                #pragma unroll
                for (int e2 = 0; e2 < NELEC; ++e2)
                    a = fmaf(h[e2*FEAT + f],
                             fT[(at*NELEC + e2)*FPAD + ff], a);
            }
            agg[n*FEAT + f] = a;
        }
    }
}

// dense update, in place: h[i] += tanh(agg[i] @ wl + bl). Each element is
// RMW'd by exactly one thread; message reads of h are barrier-separated.
__device__ __forceinline__ void dense_update(const float* __restrict__ agg,
                                             float* __restrict__ h,
                                             const float* __restrict__ wlL,
                                             const float* __restrict__ blL,
                                             int N, int w, int lane)
{
    for (int i = w; i < N; i += NWAVES) {
        float a2 = 0.f;
        const float4* arow = reinterpret_cast<const float4*>(agg + i*FEAT);
        #pragma unroll
        for (int k = 0; k < FEAT/4; ++k) {
            float4 av = arow[k];                      // uniform -> LDS broadcast
            a2 = fmaf(av.x, wlL[(4*k+0)*FEAT + lane], a2);
            a2 = fmaf(av.y, wlL[(4*k+1)*FEAT + lane], a2);
            a2 = fmaf(av.z, wlL[(4*k+2)*FEAT + lane], a2);
            a2 = fmaf(av.w, wlL[(4*k+3)*FEAT + lane], a2);
        }
        h[i*FEAT + lane] += tanhf(a2 + blL[lane]);
    }
}

// ==========================================================================
// Fused ee+en GNN, feature-tiled filt, 2 blocks/CU. One block per batch.
// Tile schedule per graph (fT holds ONE tile; layer 1 consumes t1-then-t0 so
// the filter runs 3x, not 4x):
//   F(0) | M(l0,t0) | F(1) | M(l0,t1) | D(l0) | M(l1,t1) | F(0) | M(l1,t0) | D(l1)
// ==========================================================================
__global__ __launch_bounds__(BLOCK)
void fused_kernel(const float* __restrict__ pos,
                  const float* __restrict__ atoms,
                  const float* __restrict__ emb_ee,
                  const float* __restrict__ wf_ee,
                  const float* __restrict__ bf_ee,
                  const float* __restrict__ wl_ee,
                  const float* __restrict__ bl_ee,
                  const float* __restrict__ wr_ee,
                  const float* __restrict__ br_ee,
                  const float* __restrict__ emb_en,
                  const float* __restrict__ wf_en,
                  const float* __restrict__ bf_en,
                  const float* __restrict__ wl_en,
                  const float* __restrict__ bl_en,
                  const float* __restrict__ wr_en,
                  const float* __restrict__ br_en,
                  const int*   __restrict__ ee_ty,
                  const int*   __restrict__ en_ty,
                  float*       __restrict__ out)
{
    extern __shared__ float sm[];
    double* keeP = reinterpret_cast<double*>(sm + OFF_KEE);
    float*  h    = sm + H_OFF;       // [40][64]
    float*  agg  = sm + AGG_OFF;     // [40][64]
    float*  fT   = sm + FT_OFF;      // [435][33] one feature tile of filt

    const int tid  = threadIdx.x;
    const int b    = blockIdx.x;
    const int lane = tid & 63;
    const int w    = tid >> 6;
    const float* posB = pos + b*NELEC*3;

    // ---- S0: F_ee(0) (threads 0-434) || ee h-init (waves 7-15) ----
    ee_filter_tile(posB, wf_ee, bf_ee, 0, fT, tid);
    if (w >= 7) {
        for (int idx = tid - 7*64; idx < NELEC*FEAT; idx += BLOCK - 7*64) {
            int n = idx >> 6, f = idx & 63;
            h[idx] = emb_ee[ee_ty[n]*FEAT + f];
        }
    }
    __syncthreads();

    // ---- ee layer 0 ----
    ee_msg_tile(h, agg, fT, 0, tid);                 // M(l0,t0)
    __syncthreads();
    ee_filter_tile(posB, wf_ee, bf_ee, TILE, fT, tid);   // F(1)
    __syncthreads();
    ee_msg_tile(h, agg, fT, 1, tid);                 // M(l0,t1)
    __syncthreads();
    dense_update(agg, h, wl_ee, bl_ee, NELEC, w, lane);  // D(l0)
    __syncthreads();

    // ---- ee layer 1 (t1 first: fT already holds tile 1) ----
    ee_msg_tile(h, agg, fT, 1, tid);                 // M(l1,t1)
    __syncthreads();
    ee_filter_tile(posB, wf_ee, bf_ee, 0, fT, tid);  // F(0) again
    __syncthreads();
    ee_msg_tile(h, agg, fT, 0, tid);                 // M(l1,t0)
    __syncthreads();
    dense_update(agg, h, wl_ee + FEAT*FEAT, bl_ee + FEAT, NELEC, w, lane);
    __syncthreads();

    // ---- S9: ee readout (wave 15, reads h) || F_en(0) (threads 0-299) ----
    en_filter_tile(posB, atoms, wf_en, bf_en, 0, fT, tid);
    if (w == 15) {   // kee = (sum_n h[n]) . wr + br  (f64 tail)
        float s = 0.f;
        #pragma unroll
        for (int n = 0; n < NELEC; ++n) s += h[n*FEAT + lane];
        double dv = (double)s * (double)wr_ee[lane];
        #pragma unroll
        for (int o = 32; o > 0; o >>= 1) dv += __shfl_xor(dv, o, 64);
        if (lane == 0) *keeP = dv + (double)br_ee[0];
    }
    __syncthreads();

    // ---- S10: en h-init (all waves; h free after readout) ----
    #pragma unroll
    for (int pass = 0; pass < 3; ++pass) {
        const int idx = tid + pass*BLOCK;
        if (idx < NNEN*FEAT) {
            int n = idx >> 6, f = idx & 63;
            h[idx] = emb_en[en_ty[n]*FEAT + f];
        }
    }
    __syncthreads();

    // ---- en layer 0 ----
    en_msg_tile(h, agg, fT, 0, tid);                 // M(l0,t0)
    __syncthreads();
    en_filter_tile(posB, atoms, wf_en, bf_en, TILE, fT, tid);  // F(1)
    __syncthreads();
    en_msg_tile(h, agg, fT, 1, tid);                 // M(l0,t1)
    __syncthreads();
    dense_update(agg, h, wl_en, bl_en, NNEN, w, lane);
    __syncthreads();

    // ---- en layer 1 (t1 first) ----
    en_msg_tile(h, agg, fT, 1, tid);                 // M(l1,t1)
    __syncthreads();
    en_filter_tile(posB, atoms, wf_en, bf_en, 0, fT, tid);     // F(0) again
    __syncthreads();
    en_msg_tile(h, agg, fT, 0, tid);                 // M(l1,t0)
    __syncthreads();
    dense_update(agg, h, wl_en + FEAT*FEAT, bl_en + FEAT, NNEN, w, lane);
    __syncthreads();

    // ---- final readout + combine ----
    if (w == 0) {
        float s = 0.f;
        #pragma unroll
        for (int n = 0; n < NNEN; ++n) s += h[n*FEAT + lane];
        double dv = (double)s * (double)wr_en[lane];
        #pragma unroll
        for (int o = 32; o > 0; o >>= 1) dv += __shfl_xor(dv, o, 64);
        if (lane == 0) out[b] = (float)exp(dv + (double)br_en[0] + *keeP);
    }
}

// ==========================================================================
extern "C" void kernel_launch(void* const* d_in, const int* in_sizes, int n_in,
                              void* d_out, int out_size, void* d_ws, size_t ws_size,
                              hipStream_t stream) {
    const float* pos    = (const float*)d_in[0];
    const float* atoms  = (const float*)d_in[1];
    const float* emb_ee = (const float*)d_in[2];
    const float* wf_ee  = (const float*)d_in[3];
    const float* bf_ee  = (const float*)d_in[4];
    const float* wl_ee  = (const float*)d_in[5];
    const float* bl_ee  = (const float*)d_in[6];
    const float* wr_ee  = (const float*)d_in[7];
    const float* br_ee  = (const float*)d_in[8];
    const float* emb_en = (const float*)d_in[9];
    const float* wf_en  = (const float*)d_in[10];
    const float* bf_en  = (const float*)d_in[11];
    const float* wl_en  = (const float*)d_in[12];
    const float* bl_en  = (const float*)d_in[13];
    const float* wr_en  = (const float*)d_in[14];
    const float* br_en  = (const float*)d_in[15];
    const int*   ee_ty  = (const int*)d_in[18];
    const int*   en_ty  = (const int*)d_in[21];

    float* out = (float*)d_out;        // [512]

    (void)hipFuncSetAttribute((const void*)fused_kernel,
            hipFuncAttributeMaxDynamicSharedMemorySize, SM_TOTAL*(int)sizeof(float));

    fused_kernel<<<NB, BLOCK, SM_TOTAL*sizeof(float), stream>>>(
        pos, atoms,
        emb_ee, wf_ee, bf_ee, wl_ee, bl_ee, wr_ee, br_ee,
        emb_en, wf_en, bf_en, wl_en, bl_en, wr_en, br_en,
        ee_ty, en_ty, out);
}

// Round 9
// 286.598 us; speedup vs baseline: 1.5053x; 1.5053x over previous
//
#include <hip/hip_runtime.h>
#include <math.h>

#define NB      512
#define NELEC   30
#define NATOMS  10
#define NNEN    40      // en graph nodes: 30 electrons + 10 atoms
#define FEAT    64
#define KRBF    64
#define NPEE    435     // unique elec-elec pairs
#define NPEN    300     // unique elec-nuc pairs
#define TILE    32      // feature tile per filter thread (pair-half)

// triangular pair index base for row i (i<j pairs of 30 electrons)
__device__ __forceinline__ int ee_base(int i) { return 29*i - ((i*(i-1))>>1); }

// ==========================================================================
// RBF filter core: dst[0..31] = tanh(bf[uoff+f] + sum_k exp(-(dd-ck)^2) *
// wf[k][uoff+f]).  uoff is a readfirstlane SGPR at every call site -> wf/bf
// rows are wave-uniform s_loads (scalar pipe).  facc[32] is born and dies
// inside one call (no cross-barrier register state — R5 lesson).
// FP value sequence identical to all passing rounds.
// ==========================================================================
__device__ __forceinline__ void rbf_core(float dd, const float* __restrict__ wf,
                                         const float* __restrict__ bf,
                                         int uoff, float* __restrict__ dst)
{
    float facc[TILE];
    const float* bfH = bf + uoff;                    // uniform -> s_load
    #pragma unroll
    for (int f = 0; f < TILE; ++f) facc[f] = bfH[f];
    #pragma unroll 4
    for (int k = 0; k < KRBF; ++k) {
        const float ck = (float)((double)k * (8.0/63.0));
        const float t  = dd - ck;
        const float rk = expf(-t*t);
        const float* wrow = wf + k*FEAT + uoff;      // uniform row -> s_load
        #pragma unroll
        for (int f = 0; f < TILE; ++f) facc[f] = fmaf(rk, wrow[f], facc[f]);
    }
    #pragma unroll
    for (int ff = 0; ff < TILE; ++ff) dst[ff] = tanhf(facc[ff]);
}

// ==========================================================================
// Per-wave interaction layers (R7 structure), filt row stride FP (template:
// 64 for the split-K2 path, 65 for the fused fallback).
// ==========================================================================
template<int FP>
__device__ __forceinline__ void ee_layer(const float* __restrict__ hc,
                                         float* __restrict__ hn,
                                         const float* __restrict__ filt,
                                         float* __restrict__ wr,
                                         const float* __restrict__ wlL,
                                         const float* __restrict__ blL,
                                         int w, int lane)
{
    for (int i = w; i < NELEC; i += 16) {
        const int iu = __builtin_amdgcn_readfirstlane(i);   // SALU addressing
        float a = 0.f;
        #pragma unroll
        for (int j = 0; j < NELEC; ++j) {
            if (j != iu) {
                int pp = (j < iu) ? (ee_base(j) + (iu - j - 1))
                                  : (ee_base(iu) + (j - iu - 1));
                a = fmaf(hc[j*FEAT + lane], filt[pp*FP + lane], a);
            }
        }
        wr[lane] = a;                         // same-wave roundtrip
        float a2 = 0.f;
        const float4* arow = reinterpret_cast<const float4*>(wr);
        #pragma unroll
        for (int k = 0; k < FEAT/4; ++k) {
            float4 av = arow[k];              // uniform -> LDS broadcast b128
            a2 = fmaf(av.x, wlL[(4*k+0)*FEAT + lane], a2);
            a2 = fmaf(av.y, wlL[(4*k+1)*FEAT + lane], a2);
            a2 = fmaf(av.z, wlL[(4*k+2)*FEAT + lane], a2);
            a2 = fmaf(av.w, wlL[(4*k+3)*FEAT + lane], a2);
        }
        hn[iu*FEAT + lane] = hc[iu*FEAT + lane] + tanhf(a2 + blL[lane]);
    }
}

template<int FP>
__device__ __forceinline__ void en_layer(const float* __restrict__ hc,
                                         float* __restrict__ hn,
                                         const float* __restrict__ filt,
                                         float* __restrict__ wr,
                                         const float* __restrict__ wlL,
                                         const float* __restrict__ blL,
                                         int w, int lane)
{
    for (int n = w; n < NNEN; n += 16) {
        const int nu = __builtin_amdgcn_readfirstlane(n);
        float a = 0.f;
        if (nu < NELEC) {            // electron node: atoms ascending
            #pragma unroll
            for (int at = 0; at < NATOMS; ++at)
                a = fmaf(hc[(NELEC+at)*FEAT + lane],
                         filt[(at*NELEC + nu)*FP + lane], a);
        } else {                     // atom node: electrons ascending
            const int at = nu - NELEC;
            #pragma unroll
            for (int e2 = 0; e2 < NELEC; ++e2)
                a = fmaf(hc[e2*FEAT + lane],
                         filt[(at*NELEC + e2)*FP + lane], a);
        }
        wr[lane] = a;
        float a2 = 0.f;
        const float4* arow = reinterpret_cast<const float4*>(wr);
        #pragma unroll
        for (int k = 0; k < FEAT/4; ++k) {
            float4 av = arow[k];
            a2 = fmaf(av.x, wlL[(4*k+0)*FEAT + lane], a2);
            a2 = fmaf(av.y, wlL[(4*k+1)*FEAT + lane], a2);
            a2 = fmaf(av.z, wlL[(4*k+2)*FEAT + lane], a2);
            a2 = fmaf(av.w, wlL[(4*k+3)*FEAT + lane], a2);
        }
        hn[nu*FEAT + lane] = hc[nu*FEAT + lane] + tanhf(a2 + blL[lane]);
    }
}

// ==========================================================================
// K1: filter kernel. Zero LDS, ~50 VGPR -> 8 waves/SIMD (2x the fused
// kernel's latency hiding — the R1-R8 plateau's pole). Thread = (batch,
// pair, half); wave-aligned padding keeps half/graph wave-uniform so weight
// rows stay s_loads. Writes filt rows [pair][64] to global workspace.
// ==========================================================================
#define K1_BLOCK 256
#define EE_PAD   448            // 870 ee items -> [2][448], 448 = 7 waves
#define EN_PAD   320            // 600 en items -> [2][320], 320 = 5 waves
#define K1_BPB   6              // (2*448 + 2*320) / 256 = 1536/256
#define K1_GRID  (NB * K1_BPB)  // 3072

__global__ __launch_bounds__(K1_BLOCK)
void filter_kernel(const float* __restrict__ pos,
                   const float* __restrict__ atoms,
                   const float* __restrict__ wf_ee,
                   const float* __restrict__ bf_ee,
                   const float* __restrict__ wf_en,
                   const float* __restrict__ bf_en,
                   float* __restrict__ fee,     // [NB][435][64]
                   float* __restrict__ fen)     // [NB][300][64]
{
    const int tid = threadIdx.x;
    const int bb  = blockIdx.x;
    const int b   = bb / K1_BPB;
    const int r   = (bb - b*K1_BPB)*K1_BLOCK + tid;   // 0..1535
    const float* posB = pos + b*NELEC*3;

    if (r < 2*EE_PAD) {                  // wave-uniform branch (896 = 14 waves)
        const int half = r / EE_PAD;     // wave-uniform (448 = 7 waves)
        const int p    = r - half*EE_PAD;
        if (p < NPEE) {
            int i = 0, rem = p;
            while (rem >= NELEC - 1 - i) { rem -= NELEC - 1 - i; ++i; }
            const int j = i + 1 + rem;
            const float dx = posB[3*i+0] - posB[3*j+0];
            const float dy = posB[3*i+1] - posB[3*j+1];
            const float dz = posB[3*i+2] - posB[3*j+2];
            const float dd = sqrtf(dx*dx + dy*dy + dz*dz);
            const int uoff = __builtin_amdgcn_readfirstlane(half*TILE);
            rbf_core(dd, wf_ee, bf_ee, uoff,
                     fee + (size_t)(b*NPEE + p)*FEAT + uoff);
        }
    } else {
        const int r2   = r - 2*EE_PAD;
        const int half = r2 / EN_PAD;    // wave-uniform (320 = 5 waves)
        const int p    = r2 - half*EN_PAD;
        if (p < NPEN) {
            const int a = p / NELEC;
            const int e = p - a*NELEC;
            const float dx = posB[3*e+0] - atoms[3*a+0];
            const float dy = posB[3*e+1] - atoms[3*a+1];
            const float dz = posB[3*e+2] - atoms[3*a+2];
            const float dd = sqrtf(dx*dx + dy*dy + dz*dz);
            const int uoff = __builtin_amdgcn_readfirstlane(half*TILE);
            rbf_core(dd, wf_en, bf_en, uoff,
                     fen + (size_t)(b*NPEN + p)*FEAT + uoff);
        }
    }
}

// ==========================================================================
// K2: layers kernel. One block per batch. Stages filt from global with
// identity float4 copies, then runs R7's exact layer/readout sequence.
// LDS: kee | h0[40][64] | h1[40][64] | wr[16][64] | fT[435][64] = 135952 B.
// ==========================================================================
#define BLOCK  1024
#define NWAVES 16
#define L_KEE  0
#define L_H0   4
#define L_H1   (L_H0 + NNEN*FEAT)      // 2564
#define L_WR   (L_H1 + NNEN*FEAT)      // 5124
#define L_FT   (L_WR + NWAVES*64)      // 6148 (byte 24592, 16B aligned)
#define L_TOT  (L_FT + NPEE*FEAT)      // 33988 floats = 135952 B -> 1 block/CU

__global__ __launch_bounds__(BLOCK)
void layers_kernel(const float* __restrict__ emb_ee,
                   const float* __restrict__ wl_ee,
                   const float* __restrict__ bl_ee,
                   const float* __restrict__ wr_ee,
                   const float* __restrict__ br_ee,
                   const float* __restrict__ emb_en,
                   const float* __restrict__ wl_en,
                   const float* __restrict__ bl_en,
                   const float* __restrict__ wr_en,
                   const float* __restrict__ br_en,
                   const int*   __restrict__ ee_ty,
                   const int*   __restrict__ en_ty,
                   const float* __restrict__ fee,
                   const float* __restrict__ fen,
                   float*       __restrict__ out)
{
    extern __shared__ float sm[];
    double* keeP = reinterpret_cast<double*>(sm + L_KEE);
    float*  h0   = sm + L_H0;
    float*  h1   = sm + L_H1;
    float*  wrS  = sm + L_WR;
    float*  fT   = sm + L_FT;        // [435][64]

    const int tid  = threadIdx.x;
    const int b    = blockIdx.x;
    const int lane = tid & 63;
    const int w    = tid >> 6;
    float* wr = wrS + w*64;

    // ---- S0: stage ee filt (6960 float4) + ee h0-init ----
    {
        const float4* src = reinterpret_cast<const float4*>(fee + (size_t)b*NPEE*FEAT);
        float4* dst = reinterpret_cast<float4*>(fT);
        for (int idx = tid; idx < NPEE*FEAT/4; idx += BLOCK) dst[idx] = src[idx];
    }
    for (int idx = tid; idx < NELEC*FEAT; idx += BLOCK) {
        int n = idx >> 6, f = idx & 63;
        h0[idx] = emb_ee[ee_ty[n]*FEAT + f];
    }
    __syncthreads();

    // ---- ee interaction layers ----
    ee_layer<FEAT>(h0, h1, fT, wr, wl_ee, bl_ee, w, lane);
    __syncthreads();
    ee_layer<FEAT>(h1, h0, fT, wr, wl_ee + FEAT*FEAT, bl_ee + FEAT, w, lane);
    __syncthreads();

    // ---- S3: ee readout (w15, h0) || stage en filt || en h1-init ----
    {
        const float4* src = reinterpret_cast<const float4*>(fen + (size_t)b*NPEN*FEAT);
        float4* dst = reinterpret_cast<float4*>(fT);
        for (int idx = tid; idx < NPEN*FEAT/4; idx += BLOCK) dst[idx] = src[idx];
    }
    for (int idx = tid; idx < NNEN*FEAT; idx += BLOCK) {
        int n = idx >> 6, f = idx & 63;
        h1[idx] = emb_en[en_ty[n]*FEAT + f];
    }
    if (w == 15) {   // kee = (sum_n h0[n]) . wr + br  (f64 tail)
        float s = 0.f;
        #pragma unroll
        for (int n = 0; n < NELEC; ++n) s += h0[n*FEAT + lane];
        double dv = (double)s * (double)wr_ee[lane];
        #pragma unroll
        for (int o = 32; o > 0; o >>= 1) dv += __shfl_xor(dv, o, 64);
        if (lane == 0) *keeP = dv + (double)br_ee[0];
    }
    __syncthreads();

    // ---- en interaction layers ----
    en_layer<FEAT>(h1, h0, fT, wr, wl_en, bl_en, w, lane);
    __syncthreads();
    en_layer<FEAT>(h0, h1, fT, wr, wl_en + FEAT*FEAT, bl_en + FEAT, w, lane);
    __syncthreads();

    // ---- final readout + combine ----
    if (w == 0) {
        float s = 0.f;
        #pragma unroll
        for (int n = 0; n < NNEN; ++n) s += h1[n*FEAT + lane];
        double dv = (double)s * (double)wr_en[lane];
        #pragma unroll
        for (int o = 32; o > 0; o >>= 1) dv += __shfl_xor(dv, o, 64);
        if (lane == 0) out[b] = (float)exp(dv + (double)br_en[0] + *keeP);
    }
}

// ==========================================================================
// Fallback: R7 fused kernel verbatim (best known single-kernel, 132 us) —
// used when the workspace can't hold the 96.3 MB filt buffers.
// ==========================================================================
#define FB_FPAD  65
#define FB_KEE   0
#define FB_H0    4
#define FB_H1    (FB_H0 + NNEN*FEAT)       // 2564
#define FB_FILT  (FB_H1 + NNEN*FEAT)       // 5124
#define FB_WR    33400                     // 5124 + 435*65 = 33399, +1 align
#define FB_TOT   (FB_WR + NWAVES*64)       // 34424 floats = 137696 B

__global__ __launch_bounds__(BLOCK)
void fused_kernel(const float* __restrict__ pos,
                  const float* __restrict__ atoms,
                  const float* __restrict__ emb_ee,
                  const float* __restrict__ wf_ee,
                  const float* __restrict__ bf_ee,
                  const float* __restrict__ wl_ee,
                  const float* __restrict__ bl_ee,
                  const float* __restrict__ wr_ee,
                  const float* __restrict__ br_ee,
                  const float* __restrict__ emb_en,
                  const float* __restrict__ wf_en,
                  const float* __restrict__ bf_en,
                  const float* __restrict__ wl_en,
                  const float* __restrict__ bl_en,
                  const float* __restrict__ wr_en,
                  const float* __restrict__ br_en,
                  const int*   __restrict__ ee_ty,
                  const int*   __restrict__ en_ty,
                  float*       __restrict__ out)
{
    extern __shared__ float sm[];
    double* keeP = reinterpret_cast<double*>(sm + FB_KEE);
    float*  h0   = sm + FB_H0;
    float*  h1   = sm + FB_H1;
    float*  filt = sm + FB_FILT;     // [435][65]
    float*  wrS  = sm + FB_WR;

    const int tid  = threadIdx.x;
    const int b    = blockIdx.x;
    const int lane = tid & 63;
    const int w    = tid >> 6;
    float* wr = wrS + w*64;
    const float* posB = pos + b*NELEC*3;

    const int  ee_t   = (w >= 7) ? 1 : 0;
    const int  ee_p   = ((w >= 7 ? w - 7 : w) << 6) | lane;
    const bool ee_ok  = (w < 14) && (ee_p < NPEE);
    const int  v      = w & 7;
    const int  en_blk = (w < 8) ? (v < 5 ? v : -1)
                                : ((v >= 1 && v <= 3) ? v - 1
                                   : (v == 5 || v == 6) ? v - 2 : -1);
    const int  en_t   = (w >= 8) ? 1 : 0;
    const int  en_p   = (en_blk < 0) ? 0 : ((en_blk << 6) | lane);
    const bool en_ok  = (en_blk >= 0) && (en_p < NPEN);
    const int  hr     = (w == 5) ? 0 : (w == 6) ? 1 : (w == 7) ? 2
                      : (w == 8) ? 3 : (w == 12) ? 4 : -1;
    const int uoff_ee = __builtin_amdgcn_readfirstlane(ee_t * TILE);
    const int uoff_en = __builtin_amdgcn_readfirstlane(en_t * TILE);

    if (ee_ok) {
        int i = 0, rem = ee_p;
        while (rem >= NELEC - 1 - i) { rem -= NELEC - 1 - i; ++i; }
        const int j = i + 1 + rem;
        const float dx = posB[3*i+0] - posB[3*j+0];
        const float dy = posB[3*i+1] - posB[3*j+1];
        const float dz = posB[3*i+2] - posB[3*j+2];
        const float dd = sqrtf(dx*dx + dy*dy + dz*dz);
        rbf_core(dd, wf_ee, bf_ee, uoff_ee, filt + ee_p*FB_FPAD + uoff_ee);
    }
    if (w >= 14) {
        for (int idx = tid - 14*64; idx < NELEC*FEAT; idx += BLOCK - 14*64) {
            int n = idx >> 6, f = idx & 63;
            h0[idx] = emb_ee[ee_ty[n]*FEAT + f];
        }
    }
    __syncthreads();

    ee_layer<FB_FPAD>(h0, h1, filt, wr, wl_ee, bl_ee, w, lane);
    __syncthreads();
    ee_layer<FB_FPAD>(h1, h0, filt, wr, wl_ee + FEAT*FEAT, bl_ee + FEAT, w, lane);
    __syncthreads();

    if (en_ok) {
        const int a = en_p / NELEC;
        const int e = en_p - a*NELEC;
        const float dx = posB[3*e+0] - atoms[3*a+0];
        const float dy = posB[3*e+1] - atoms[3*a+1];
        const float dz = posB[3*e+2] - atoms[3*a+2];
        const float dd = sqrtf(dx*dx + dy*dy + dz*dz);
        rbf_core(dd, wf_en, bf_en, uoff_en, filt + en_p*FB_FPAD + uoff_en);
    }
    if (hr >= 0) {
        #pragma unroll
        for (int r = 0; r < 8; ++r) {
            const int idx = hr*64 + lane + r*320;
            h1[idx] = emb_en[en_ty[idx >> 6]*FEAT + (idx & 63)];
        }
    }
    if (w == 15) {
        float s = 0.f;
        #pragma unroll
        for (int n = 0; n < NELEC; ++n) s += h0[n*FEAT + lane];
        double dv = (double)s * (double)wr_ee[lane];
        #pragma unroll
        for (int o = 32; o > 0; o >>= 1) dv += __shfl_xor(dv, o, 64);
        if (lane == 0) *keeP = dv + (double)br_ee[0];
    }
    __syncthreads();

    en_layer<FB_FPAD>(h1, h0, filt, wr, wl_en, bl_en, w, lane);
    __syncthreads();
    en_layer<FB_FPAD>(h0, h1, filt, wr, wl_en + FEAT*FEAT, bl_en + FEAT, w, lane);
    __syncthreads();

    if (w == 0) {
        float s = 0.f;
        #pragma unroll
        for (int n = 0; n < NNEN; ++n) s += h1[n*FEAT + lane];
        double dv = (double)s * (double)wr_en[lane];
        #pragma unroll
        for (int o = 32; o > 0; o >>= 1) dv += __shfl_xor(dv, o, 64);
        if (lane == 0) out[b] = (float)exp(dv + (double)br_en[0] + *keeP);
    }
}

// ==========================================================================
extern "C" void kernel_launch(void* const* d_in, const int* in_sizes, int n_in,
                              void* d_out, int out_size, void* d_ws, size_t ws_size,
                              hipStream_t stream) {
    const float* pos    = (const float*)d_in[0];
    const float* atoms  = (const float*)d_in[1];
    const float* emb_ee = (const float*)d_in[2];
    const float* wf_ee  = (const float*)d_in[3];
    const float* bf_ee  = (const float*)d_in[4];
    const float* wl_ee  = (const float*)d_in[5];
    const float* bl_ee  = (const float*)d_in[6];
    const float* wr_ee  = (const float*)d_in[7];
    const float* br_ee  = (const float*)d_in[8];
    const float* emb_en = (const float*)d_in[9];
    const float* wf_en  = (const float*)d_in[10];
    const float* bf_en  = (const float*)d_in[11];
    const float* wl_en  = (const float*)d_in[12];
    const float* bl_en  = (const float*)d_in[13];
    const float* wr_en  = (const float*)d_in[14];
    const float* br_en  = (const float*)d_in[15];
    const int*   ee_ty  = (const int*)d_in[18];
    const int*   en_ty  = (const int*)d_in[21];

    float* out = (float*)d_out;        // [512]

    const size_t need = (size_t)NB * (NPEE + NPEN) * FEAT * sizeof(float); // 96.3 MB

    if (d_ws != nullptr && ws_size >= need) {
        float* fee = (float*)d_ws;                         // [512][435][64]
        float* fen = fee + (size_t)NB * NPEE * FEAT;       // [512][300][64]

        filter_kernel<<<K1_GRID, K1_BLOCK, 0, stream>>>(
            pos, atoms, wf_ee, bf_ee, wf_en, bf_en, fee, fen);

        (void)hipFuncSetAttribute((const void*)layers_kernel,
                hipFuncAttributeMaxDynamicSharedMemorySize, L_TOT*(int)sizeof(float));
        layers_kernel<<<NB, BLOCK, L_TOT*sizeof(float), stream>>>(
            emb_ee, wl_ee, bl_ee, wr_ee, br_ee,
            emb_en, wl_en, bl_en, wr_en, br_en,
            ee_ty, en_ty, fee, fen, out);
    } else {
        (void)hipFuncSetAttribute((const void*)fused_kernel,
                hipFuncAttributeMaxDynamicSharedMemorySize, FB_TOT*(int)sizeof(float));
        fused_kernel<<<NB, BLOCK, FB_TOT*sizeof(float), stream>>>(
            pos, atoms,
            emb_ee, wf_ee, bf_ee, wl_ee, bl_ee, wr_ee, br_ee,
            emb_en, wf_en, bf_en, wl_en, bl_en, wr_en, br_en,
            ee_ty, en_ty, out);
    }
}

// Round 10
// 216.707 us; speedup vs baseline: 1.9908x; 1.3225x over previous
//
#include <hip/hip_runtime.h>
#include <math.h>

#define NB      512
#define NELEC   30
#define NATOMS  10
#define NNEN    40      // en graph nodes: 30 electrons + 10 atoms
#define FEAT    64
#define KRBF    64
#define NPEE    435     // unique elec-elec pairs
#define NPEN    300     // unique elec-nuc pairs
#define TILE    32      // feature tile per filter thread (pair-half)
#define BLOCK   1024
#define NWAVES  16

// triangular pair index base for row i (i<j pairs of 30 electrons)
__device__ __forceinline__ int ee_base(int i) { return 29*i - ((i*(i-1))>>1); }

// ==========================================================================
// RBF filter core (fallback version, R7-identical): writes tanh'd tile to
// dst (LDS). uoff is an SGPR at all call sites -> weight rows are s_loads.
// ==========================================================================
__device__ __forceinline__ void rbf_core(float dd, const float* __restrict__ wf,
                                         const float* __restrict__ bf,
                                         int uoff, float* __restrict__ dst)
{
    float facc[TILE];
    const float* bfH = bf + uoff;                    // uniform -> s_load
    #pragma unroll
    for (int f = 0; f < TILE; ++f) facc[f] = bfH[f];
    #pragma unroll 4
    for (int k = 0; k < KRBF; ++k) {
        const float ck = (float)((double)k * (8.0/63.0));
        const float t  = dd - ck;
        const float rk = expf(-t*t);
        const float* wrow = wf + k*FEAT + uoff;      // uniform row -> s_load
        #pragma unroll
        for (int f = 0; f < TILE; ++f) facc[f] = fmaf(rk, wrow[f], facc[f]);
    }
    #pragma unroll
    for (int ff = 0; ff < TILE; ++ff) dst[ff] = tanhf(facc[ff]);
}

// ==========================================================================
// RBF filter into registers (K1 version). The empty volatile asm pins rk in
// a VGPR once per k: R9's compiler loop-interchange (f outer, k inner —
// VGPR=24, 32x expf recompute, 151 us) becomes illegal because volatile asm
// cannot be rematerialized per-f. Value chain bit-identical to rbf_core.
// ==========================================================================
__device__ __forceinline__ void rbf_regs(float dd, const float* __restrict__ wf,
                                         const float* __restrict__ bf,
                                         int uoff, float* __restrict__ facc)
{
    const float* bfH = bf + uoff;
    #pragma unroll
    for (int f = 0; f < TILE; ++f) facc[f] = bfH[f];
    #pragma unroll 4
    for (int k = 0; k < KRBF; ++k) {
        const float ck = (float)((double)k * (8.0/63.0));
        const float t  = dd - ck;
        float rk = expf(-t*t);
        asm volatile("" : "+v"(rk));                 // forbid per-f recompute
        const float* wrow = wf + k*FEAT + uoff;      // uniform row -> s_load
        #pragma unroll
        for (int f = 0; f < TILE; ++f) facc[f] = fmaf(rk, wrow[f], facc[f]);
    }
    #pragma unroll
    for (int f = 0; f < TILE; ++f) facc[f] = tanhf(facc[f]);
}

// ==========================================================================
// K1: filter kernel. Zero LDS; 1024-thread blocks; launch_bounds(1024,8)
// = 8 waves/EU target -> 2 blocks/CU co-resident (VGPR cap 64), doubling
// the filter's latency hiding vs the fused kernel's 4 waves/SIMD lockstep.
// Thread = (batch, pair, half); wave-aligned padding keeps batch/half
// wave-uniform (readfirstlane) so weight rows stay s_loads.
// ==========================================================================
#define EE_PAD  448             // 2x448 ee slots (7 waves per half)
#define EN_PAD  320             // 2x320 en slots (5 waves per half)
#define SLOTS   1536            // per batch
#define K1_GRID ((NB*SLOTS)/BLOCK)   // 768

__global__ __launch_bounds__(BLOCK, 8)
void filter_kernel(const float* __restrict__ pos,
                   const float* __restrict__ atoms,
                   const float* __restrict__ wf_ee,
                   const float* __restrict__ bf_ee,
                   const float* __restrict__ wf_en,
                   const float* __restrict__ bf_en,
                   float* __restrict__ fee,     // [NB][435][64]
                   float* __restrict__ fen)     // [NB][300][64]
{
    const int slot = blockIdx.x*BLOCK + threadIdx.x;
    const int b    = __builtin_amdgcn_readfirstlane(slot / SLOTS);
    const int r    = slot - b*SLOTS;
    const float* posB = pos + b*NELEC*3;

    float facc[TILE];
    if (r < 2*EE_PAD) {
        const int half = __builtin_amdgcn_readfirstlane(r / EE_PAD);
        const int p    = r - half*EE_PAD;
        if (p < NPEE) {
            int i = 0, rem = p;
            while (rem >= NELEC - 1 - i) { rem -= NELEC - 1 - i; ++i; }
            const int j = i + 1 + rem;
            const float dx = posB[3*i+0] - posB[3*j+0];
            const float dy = posB[3*i+1] - posB[3*j+1];
            const float dz = posB[3*i+2] - posB[3*j+2];
            const float dd = sqrtf(dx*dx + dy*dy + dz*dz);
            rbf_regs(dd, wf_ee, bf_ee, half*TILE, facc);
            float4* dst = reinterpret_cast<float4*>(
                fee + ((size_t)b*NPEE + p)*FEAT + half*TILE);
            #pragma unroll
            for (int v = 0; v < TILE/4; ++v)
                dst[v] = make_float4(facc[4*v+0], facc[4*v+1],
                                     facc[4*v+2], facc[4*v+3]);
        }
    } else {
        const int r2   = r - 2*EE_PAD;
        const int half = __builtin_amdgcn_readfirstlane(r2 / EN_PAD);
        const int p    = r2 - half*EN_PAD;
        if (p < NPEN) {
            const int a = p / NELEC;
            const int e = p - a*NELEC;
            const float dx = posB[3*e+0] - atoms[3*a+0];
            const float dy = posB[3*e+1] - atoms[3*a+1];
            const float dz = posB[3*e+2] - atoms[3*a+2];
            const float dd = sqrtf(dx*dx + dy*dy + dz*dz);
            rbf_regs(dd, wf_en, bf_en, half*TILE, facc);
            float4* dst = reinterpret_cast<float4*>(
                fen + ((size_t)b*NPEN + p)*FEAT + half*TILE);
            #pragma unroll
            for (int v = 0; v < TILE/4; ++v)
                dst[v] = make_float4(facc[4*v+0], facc[4*v+1],
                                     facc[4*v+2], facc[4*v+3]);
        }
    }
}

// ==========================================================================
// K2 helpers: split msg / dense (dense weights from LDS — the previous
// per-lane GLOBAL wl loads were 64 L2 round-trips per node per wave).
// FP chains identical to all passing rounds.
// ==========================================================================
__device__ __forceinline__ void ee_msg(const float* __restrict__ hc,
                                       float* __restrict__ agg,
                                       const float* __restrict__ fT,
                                       int w, int lane)
{
    for (int i = w; i < NELEC; i += NWAVES) {
        const int iu = __builtin_amdgcn_readfirstlane(i);
        float a = 0.f;
        #pragma unroll
        for (int j = 0; j < NELEC; ++j) {
            if (j != iu) {
                int pp = (j < iu) ? (ee_base(j) + (iu - j - 1))
                                  : (ee_base(iu) + (j - iu - 1));
                a = fmaf(hc[j*FEAT + lane], fT[pp*FEAT + lane], a);
            }
        }
        agg[iu*FEAT + lane] = a;
    }
}

__device__ __forceinline__ void en_msg(const float* __restrict__ hc,
                                       float* __restrict__ agg,
                                       const float* __restrict__ fT,
                                       int w, int lane)
{
    for (int n = w; n < NNEN; n += NWAVES) {
        const int nu = __builtin_amdgcn_readfirstlane(n);
        float a = 0.f;
        if (nu < NELEC) {            // electron node: atoms ascending
            #pragma unroll
            for (int at = 0; at < NATOMS; ++at)
                a = fmaf(hc[(NELEC+at)*FEAT + lane],
                         fT[(at*NELEC + nu)*FEAT + lane], a);
        } else {                     // atom node: electrons ascending
            const int at = nu - NELEC;
            #pragma unroll
            for (int e2 = 0; e2 < NELEC; ++e2)
                a = fmaf(hc[e2*FEAT + lane],
                         fT[(at*NELEC + e2)*FEAT + lane], a);
        }
        agg[nu*FEAT + lane] = a;
    }
}

__device__ __forceinline__ void dense_lds(const float* __restrict__ agg,
                                          const float* __restrict__ hc,
                                          float* __restrict__ hn,
                                          const float* __restrict__ wlS,
                                          const float* __restrict__ blL,
                                          int N, int w, int lane)
{
    for (int i = w; i < N; i += NWAVES) {
        const int iu = __builtin_amdgcn_readfirstlane(i);
        float a2 = 0.f;
        const float4* arow = reinterpret_cast<const float4*>(agg + iu*FEAT);
        #pragma unroll
        for (int k = 0; k < FEAT/4; ++k) {
            float4 av = arow[k];                     // uniform -> LDS broadcast
            a2 = fmaf(av.x, wlS[(4*k+0)*FEAT + lane], a2);
            a2 = fmaf(av.y, wlS[(4*k+1)*FEAT + lane], a2);
            a2 = fmaf(av.z, wlS[(4*k+2)*FEAT + lane], a2);
            a2 = fmaf(av.w, wlS[(4*k+3)*FEAT + lane], a2);
        }
        hn[iu*FEAT + lane] = hc[iu*FEAT + lane] + tanhf(a2 + blL[lane]);
    }
}

// ==========================================================================
// K2: layers kernel. One block per batch. filt staged from workspace
// (stride 64, row reads conflict-free); dense weights staged per layer
// (1 float4/thread) into wlS. LDS total 158480 B -> 1 block/CU.
// ==========================================================================
#define L2_KEE 0
#define L2_H0  4
#define L2_H1  (L2_H0 + NNEN*FEAT)      // 2564
#define L2_AGG (L2_H1 + NNEN*FEAT)      // 5124
#define L2_WLS (L2_AGG + NNEN*FEAT)     // 7684
#define L2_FT  (L2_WLS + FEAT*FEAT)     // 11780 (byte 47120, 16B aligned)
#define L2_TOT (L2_FT + NPEE*FEAT)      // 39620 floats = 158480 B

__global__ __launch_bounds__(BLOCK)
void layers_kernel(const float* __restrict__ emb_ee,
                   const float* __restrict__ wl_ee,
                   const float* __restrict__ bl_ee,
                   const float* __restrict__ wr_ee,
                   const float* __restrict__ br_ee,
                   const float* __restrict__ emb_en,
                   const float* __restrict__ wl_en,
                   const float* __restrict__ bl_en,
                   const float* __restrict__ wr_en,
                   const float* __restrict__ br_en,
                   const int*   __restrict__ ee_ty,
                   const int*   __restrict__ en_ty,
                   const float* __restrict__ fee,
                   const float* __restrict__ fen,
                   float*       __restrict__ out)
{
    extern __shared__ float sm[];
    double* keeP = reinterpret_cast<double*>(sm + L2_KEE);
    float*  h0   = sm + L2_H0;
    float*  h1   = sm + L2_H1;
    float*  agg  = sm + L2_AGG;
    float*  wlS  = sm + L2_WLS;      // [64][64] current layer's dense weights
    float*  fT   = sm + L2_FT;       // [435][64]

    const int tid  = threadIdx.x;
    const int b    = blockIdx.x;
    const int lane = tid & 63;
    const int w    = tid >> 6;

    // ---- S0: stage ee filt + ee h0-init ----
    {
        const float4* src = reinterpret_cast<const float4*>(fee + (size_t)b*NPEE*FEAT);
        float4* dst = reinterpret_cast<float4*>(fT);
        for (int idx = tid; idx < NPEE*FEAT/4; idx += BLOCK) dst[idx] = src[idx];
    }
    for (int idx = tid; idx < NELEC*FEAT; idx += BLOCK)
        h0[idx] = emb_ee[ee_ty[idx >> 6]*FEAT + (idx & 63)];
    __syncthreads();

    // ---- ee layer 0: {stage wl0 || msg} bar {dense} bar ----
    reinterpret_cast<float4*>(wlS)[tid] =
        reinterpret_cast<const float4*>(wl_ee)[tid];
    ee_msg(h0, agg, fT, w, lane);
    __syncthreads();
    dense_lds(agg, h0, h1, wlS, bl_ee, NELEC, w, lane);
    __syncthreads();

    // ---- ee layer 1 ----
    reinterpret_cast<float4*>(wlS)[tid] =
        reinterpret_cast<const float4*>(wl_ee + FEAT*FEAT)[tid];
    ee_msg(h1, agg, fT, w, lane);
    __syncthreads();
    dense_lds(agg, h1, h0, wlS, bl_ee + FEAT, NELEC, w, lane);
    __syncthreads();

    // ---- S3: ee readout (w15, h0) || stage en filt || en h1-init ----
    {
        const float4* src = reinterpret_cast<const float4*>(fen + (size_t)b*NPEN*FEAT);
        float4* dst = reinterpret_cast<float4*>(fT);
        for (int idx = tid; idx < NPEN*FEAT/4; idx += BLOCK) dst[idx] = src[idx];
    }
    for (int idx = tid; idx < NNEN*FEAT; idx += BLOCK)
        h1[idx] = emb_en[en_ty[idx >> 6]*FEAT + (idx & 63)];
    if (w == 15) {   // kee = (sum_n h0[n]) . wr + br  (f64 tail)
        float s = 0.f;
        #pragma unroll
        for (int n = 0; n < NELEC; ++n) s += h0[n*FEAT + lane];
        double dv = (double)s * (double)wr_ee[lane];
        #pragma unroll
        for (int o = 32; o > 0; o >>= 1) dv += __shfl_xor(dv, o, 64);
        if (lane == 0) *keeP = dv + (double)br_ee[0];
    }
    __syncthreads();

    // ---- en layer 0 ----
    reinterpret_cast<float4*>(wlS)[tid] =
        reinterpret_cast<const float4*>(wl_en)[tid];
    en_msg(h1, agg, fT, w, lane);
    __syncthreads();
    dense_lds(agg, h1, h0, wlS, bl_en, NNEN, w, lane);
    __syncthreads();

    // ---- en layer 1 ----
    reinterpret_cast<float4*>(wlS)[tid] =
        reinterpret_cast<const float4*>(wl_en + FEAT*FEAT)[tid];
    en_msg(h0, agg, fT, w, lane);
    __syncthreads();
    dense_lds(agg, h0, h1, wlS, bl_en + FEAT, NNEN, w, lane);
    __syncthreads();

    // ---- final readout + combine ----
    if (w == 0) {
        float s = 0.f;
        #pragma unroll
        for (int n = 0; n < NNEN; ++n) s += h1[n*FEAT + lane];
        double dv = (double)s * (double)wr_en[lane];
        #pragma unroll
        for (int o = 32; o > 0; o >>= 1) dv += __shfl_xor(dv, o, 64);
        if (lane == 0) out[b] = (float)exp(dv + (double)br_en[0] + *keeP);
    }
}

// ==========================================================================
// Fallback fused kernel (R7 verbatim, 132 us) + its template layers —
// used when the workspace can't hold the 96.3 MB filt buffers.
// ==========================================================================
template<int FP>
__device__ __forceinline__ void ee_layer(const float* __restrict__ hc,
                                         float* __restrict__ hn,
                                         const float* __restrict__ filt,
                                         float* __restrict__ wr,
                                         const float* __restrict__ wlL,
                                         const float* __restrict__ blL,
                                         int w, int lane)
{
    for (int i = w; i < NELEC; i += NWAVES) {
        const int iu = __builtin_amdgcn_readfirstlane(i);
        float a = 0.f;
        #pragma unroll
        for (int j = 0; j < NELEC; ++j) {
            if (j != iu) {
                int pp = (j < iu) ? (ee_base(j) + (iu - j - 1))
                                  : (ee_base(iu) + (j - iu - 1));
                a = fmaf(hc[j*FEAT + lane], filt[pp*FP + lane], a);
            }
        }
        wr[lane] = a;
        float a2 = 0.f;
        const float4* arow = reinterpret_cast<const float4*>(wr);
        #pragma unroll
        for (int k = 0; k < FEAT/4; ++k) {
            float4 av = arow[k];
            a2 = fmaf(av.x, wlL[(4*k+0)*FEAT + lane], a2);
            a2 = fmaf(av.y, wlL[(4*k+1)*FEAT + lane], a2);
            a2 = fmaf(av.z, wlL[(4*k+2)*FEAT + lane], a2);
            a2 = fmaf(av.w, wlL[(4*k+3)*FEAT + lane], a2);
        }
        hn[iu*FEAT + lane] = hc[iu*FEAT + lane] + tanhf(a2 + blL[lane]);
    }
}

template<int FP>
__device__ __forceinline__ void en_layer(const float* __restrict__ hc,
                                         float* __restrict__ hn,
                                         const float* __restrict__ filt,
                                         float* __restrict__ wr,
                                         const float* __restrict__ wlL,
                                         const float* __restrict__ blL,
                                         int w, int lane)
{
    for (int n = w; n < NNEN; n += NWAVES) {
        const int nu = __builtin_amdgcn_readfirstlane(n);
        float a = 0.f;
        if (nu < NELEC) {
            #pragma unroll
            for (int at = 0; at < NATOMS; ++at)
                a = fmaf(hc[(NELEC+at)*FEAT + lane],
                         filt[(at*NELEC + nu)*FP + lane], a);
        } else {
            const int at = nu - NELEC;
            #pragma unroll
            for (int e2 = 0; e2 < NELEC; ++e2)
                a = fmaf(hc[e2*FEAT + lane],
                         filt[(at*NELEC + e2)*FP + lane], a);
        }
        wr[lane] = a;
        float a2 = 0.f;
        const float4* arow = reinterpret_cast<const float4*>(wr);
        #pragma unroll
        for (int k = 0; k < FEAT/4; ++k) {
            float4 av = arow[k];
            a2 = fmaf(av.x, wlL[(4*k+0)*FEAT + lane], a2);
            a2 = fmaf(av.y, wlL[(4*k+1)*FEAT + lane], a2);
            a2 = fmaf(av.z, wlL[(4*k+2)*FEAT + lane], a2);
            a2 = fmaf(av.w, wlL[(4*k+3)*FEAT + lane], a2);
        }
        hn[nu*FEAT + lane] = hc[nu*FEAT + lane] + tanhf(a2 + blL[lane]);
    }
}

#define FB_FPAD  65
#define FB_KEE   0
#define FB_H0    4
#define FB_H1    (FB_H0 + NNEN*FEAT)       // 2564
#define FB_FILT  (FB_H1 + NNEN*FEAT)       // 5124
#define FB_WR    33400                     // 5124 + 435*65 = 33399, +1 align
#define FB_TOT   (FB_WR + NWAVES*64)       // 34424 floats = 137696 B

__global__ __launch_bounds__(BLOCK)
void fused_kernel(const float* __restrict__ pos,
                  const float* __restrict__ atoms,
                  const float* __restrict__ emb_ee,
                  const float* __restrict__ wf_ee,
                  const float* __restrict__ bf_ee,
                  const float* __restrict__ wl_ee,
                  const float* __restrict__ bl_ee,
                  const float* __restrict__ wr_ee,
                  const float* __restrict__ br_ee,
                  const float* __restrict__ emb_en,
                  const float* __restrict__ wf_en,
                  const float* __restrict__ bf_en,
                  const float* __restrict__ wl_en,
                  const float* __restrict__ bl_en,
                  const float* __restrict__ wr_en,
                  const float* __restrict__ br_en,
                  const int*   __restrict__ ee_ty,
                  const int*   __restrict__ en_ty,
                  float*       __restrict__ out)
{
    extern __shared__ float sm[];
    double* keeP = reinterpret_cast<double*>(sm + FB_KEE);
    float*  h0   = sm + FB_H0;
    float*  h1   = sm + FB_H1;
    float*  filt = sm + FB_FILT;
    float*  wrS  = sm + FB_WR;

    const int tid  = threadIdx.x;
    const int b    = blockIdx.x;
    const int lane = tid & 63;
    const int w    = tid >> 6;
    float* wr = wrS + w*64;
    const float* posB = pos + b*NELEC*3;

    const int  ee_t   = (w >= 7) ? 1 : 0;
    const int  ee_p   = ((w >= 7 ? w - 7 : w) << 6) | lane;
    const bool ee_ok  = (w < 14) && (ee_p < NPEE);
    const int  v      = w & 7;
    const int  en_blk = (w < 8) ? (v < 5 ? v : -1)
                                : ((v >= 1 && v <= 3) ? v - 1
                                   : (v == 5 || v == 6) ? v - 2 : -1);
    const int  en_t   = (w >= 8) ? 1 : 0;
    const int  en_p   = (en_blk < 0) ? 0 : ((en_blk << 6) | lane);
    const bool en_ok  = (en_blk >= 0) && (en_p < NPEN);
    const int  hr     = (w == 5) ? 0 : (w == 6) ? 1 : (w == 7) ? 2
                      : (w == 8) ? 3 : (w == 12) ? 4 : -1;
    const int uoff_ee = __builtin_amdgcn_readfirstlane(ee_t * TILE);
    const int uoff_en = __builtin_amdgcn_readfirstlane(en_t * TILE);

    if (ee_ok) {
        int i = 0, rem = ee_p;
        while (rem >= NELEC - 1 - i) { rem -= NELEC - 1 - i; ++i; }
        const int j = i + 1 + rem;
        const float dx = posB[3*i+0] - posB[3*j+0];
        const float dy = posB[3*i+1] - posB[3*j+1];
        const float dz = posB[3*i+2] - posB[3*j+2];
        const float dd = sqrtf(dx*dx + dy*dy + dz*dz);
        rbf_core(dd, wf_ee, bf_ee, uoff_ee, filt + ee_p*FB_FPAD + uoff_ee);
    }
    if (w >= 14) {
        for (int idx = tid - 14*64; idx < NELEC*FEAT; idx += BLOCK - 14*64) {
            int n = idx >> 6, f = idx & 63;
            h0[idx] = emb_ee[ee_ty[n]*FEAT + f];
        }
    }
    __syncthreads();

    ee_layer<FB_FPAD>(h0, h1, filt, wr, wl_ee, bl_ee, w, lane);
    __syncthreads();
    ee_layer<FB_FPAD>(h1, h0, filt, wr, wl_ee + FEAT*FEAT, bl_ee + FEAT, w, lane);
    __syncthreads();

    if (en_ok) {
        const int a = en_p / NELEC;
        const int e = en_p - a*NELEC;
        const float dx = posB[3*e+0] - atoms[3*a+0];
        const float dy = posB[3*e+1] - atoms[3*a+1];
        const float dz = posB[3*e+2] - atoms[3*a+2];
        const float dd = sqrtf(dx*dx + dy*dy + dz*dz);
        rbf_core(dd, wf_en, bf_en, uoff_en, filt + en_p*FB_FPAD + uoff_en);
    }
    if (hr >= 0) {
        #pragma unroll
        for (int r = 0; r < 8; ++r) {
            const int idx = hr*64 + lane + r*320;
            h1[idx] = emb_en[en_ty[idx >> 6]*FEAT + (idx & 63)];
        }
    }
    if (w == 15) {
        float s = 0.f;
        #pragma unroll
        for (int n = 0; n < NELEC; ++n) s += h0[n*FEAT + lane];
        double dv = (double)s * (double)wr_ee[lane];
        #pragma unroll
        for (int o = 32; o > 0; o >>= 1) dv += __shfl_xor(dv, o, 64);
        if (lane == 0) *keeP = dv + (double)br_ee[0];
    }
    __syncthreads();

    en_layer<FB_FPAD>(h1, h0, filt, wr, wl_en, bl_en, w, lane);
    __syncthreads();
    en_layer<FB_FPAD>(h0, h1, filt, wr, wl_en + FEAT*FEAT, bl_en + FEAT, w, lane);
    __syncthreads();

    if (w == 0) {
        float s = 0.f;
        #pragma unroll
        for (int n = 0; n < NNEN; ++n) s += h1[n*FEAT + lane];
        double dv = (double)s * (double)wr_en[lane];
        #pragma unroll
        for (int o = 32; o > 0; o >>= 1) dv += __shfl_xor(dv, o, 64);
        if (lane == 0) out[b] = (float)exp(dv + (double)br_en[0] + *keeP);
    }
}

// ==========================================================================
extern "C" void kernel_launch(void* const* d_in, const int* in_sizes, int n_in,
                              void* d_out, int out_size, void* d_ws, size_t ws_size,
                              hipStream_t stream) {
    const float* pos    = (const float*)d_in[0];
    const float* atoms  = (const float*)d_in[1];
    const float* emb_ee = (const float*)d_in[2];
    const float* wf_ee  = (const float*)d_in[3];
    const float* bf_ee  = (const float*)d_in[4];
    const float* wl_ee  = (const float*)d_in[5];
    const float* bl_ee  = (const float*)d_in[6];
    const float* wr_ee  = (const float*)d_in[7];
    const float* br_ee  = (const float*)d_in[8];
    const float* emb_en = (const float*)d_in[9];
    const float* wf_en  = (const float*)d_in[10];
    const float* bf_en  = (const float*)d_in[11];
    const float* wl_en  = (const float*)d_in[12];
    const float* bl_en  = (const float*)d_in[13];
    const float* wr_en  = (const float*)d_in[14];
    const float* br_en  = (const float*)d_in[15];
    const int*   ee_ty  = (const int*)d_in[18];
    const int*   en_ty  = (const int*)d_in[21];

    float* out = (float*)d_out;        // [512]

    const size_t need = (size_t)NB * (NPEE + NPEN) * FEAT * sizeof(float); // 96.3 MB

    if (d_ws != nullptr && ws_size >= need) {
        float* fee = (float*)d_ws;                         // [512][435][64]
        float* fen = fee + (size_t)NB * NPEE * FEAT;       // [512][300][64]

        filter_kernel<<<K1_GRID, BLOCK, 0, stream>>>(
            pos, atoms, wf_ee, bf_ee, wf_en, bf_en, fee, fen);

        (void)hipFuncSetAttribute((const void*)layers_kernel,
                hipFuncAttributeMaxDynamicSharedMemorySize, L2_TOT*(int)sizeof(float));
        layers_kernel<<<NB, BLOCK, L2_TOT*sizeof(float), stream>>>(
            emb_ee, wl_ee, bl_ee, wr_ee, br_ee,
            emb_en, wl_en, bl_en, wr_en, br_en,
            ee_ty, en_ty, fee, fen, out);
    } else {
        (void)hipFuncSetAttribute((const void*)fused_kernel,
                hipFuncAttributeMaxDynamicSharedMemorySize, FB_TOT*(int)sizeof(float));
        fused_kernel<<<NB, BLOCK, FB_TOT*sizeof(float), stream>>>(
            pos, atoms,
            emb_ee, wf_ee, bf_ee, wl_ee, bl_ee, wr_ee, br_ee,
            emb_en, wf_en, bf_en, wl_en, bl_en, wr_en, br_en,
            ee_ty, en_ty, out);
    }
}